// Round 9
// baseline (105.428 us; speedup 1.0000x reference)
//
#include <hip/hip_runtime.h>
#include <math.h>

#define NROWS 8192
#define DDIM  128
#define K20   28.853900817779268f        // 20 * log2(e)
#define K2    (K20 * K20)                // 832.5476
#define DTHR  8.3255f                    // 0.01 * K2 : self-pair mask (real pairs >> this)

typedef _Float16 f16x8 __attribute__((ext_vector_type(8)));
typedef _Float16 f16x4 __attribute__((ext_vector_type(4)));
typedef _Float16 f16x2 __attribute__((ext_vector_type(2)));
typedef float    f32x4 __attribute__((ext_vector_type(4)));

#ifndef __has_builtin
#define __has_builtin(x) 0
#endif
#if __has_builtin(__builtin_amdgcn_fdot2)
#define HAVE_FDOT2 1
#else
#define HAVE_FDOT2 0
#endif

// Fragment-major layout for mfma_f32_16x16x32_f16 (16-row groups):
//   xf[g*2048 + kk*512 + l*8 + j] = x[i = g*16 + (l&15)][k = kk*32 + (l>>4)*8 + j]
// -> a wave's A/B fragment load for one k-chunk is one contiguous 1 KB dwordx4.
// ws layout (floats after xf): sums[0..N) = nL (sum exp(-40d)), [N..2N) = nS (sum exp(-20d))

// ---- fp32 -> f16 frag-major transform + zero sums/out ----
__global__ void convert_kernel(const float* __restrict__ x,
                               _Float16* __restrict__ xf,
                               float* __restrict__ sums,
                               float* __restrict__ out) {
    int idx = (blockIdx.x * 256 + threadIdx.x) * 4;    // flat (i,k) element index
    float4 v = *(const float4*)(x + idx);
    f16x4 h = { (_Float16)v.x, (_Float16)v.y, (_Float16)v.z, (_Float16)v.w };
    const int i = idx >> 7, k = idx & 127;             // k multiple of 4
    const int lane = (((k >> 3) & 3) << 4) | (i & 15);
    const int dst = (i >> 4) * 2048 + (k >> 5) * 512 + lane * 8 + (k & 7);
    *(f16x4*)(xf + dst) = h;
    if (threadIdx.x < 16) sums[blockIdx.x * 16 + threadIdx.x] = 0.0f;  // 1024*16 = 2*NROWS
    if (blockIdx.x == 0 && threadIdx.x == 0) out[0] = 0.0f;
}

// ---- lean-occupancy pair kernel: full matrix, wave = ONE 16-row strip x
//      256-col segment (16 tiles). State ~72 VGPR (a 16 + b dbuf 32 + acc 4 +
//      sums 8 + addr) -> fits the 85-VGPR cap of 6 waves/SIMD WITHOUT spilling
//      (round 6's failure was 2-strip state ~104 > 85 -> hot-loop spills).
//      The single experiment variable vs the verified structure: occupancy
//      4 -> 6 waves/SIMD. No LDS, no mirror, atomics only at wave end. ----
__global__ __launch_bounds__(256, 6) void pair_kernel(
        const _Float16* __restrict__ xf,
        float* __restrict__ sums) {
    const int w = threadIdx.x >> 6;
    const int lane = threadIdx.x & 63;
    const int sg = blockIdx.x * 4 + w;            // 16-row strip, 0..511
    const int i0 = sg * 16;
    const int ct0 = blockIdx.y * 16;              // first 16-col tile of segment

    // A fragments resident: 4 k-chunks, one 1 KB coalesced load each
    const _Float16* ab = xf + (size_t)sg * 2048 + lane * 8;
    f16x8 a[4];
    #pragma unroll
    for (int kk = 0; kk < 4; ++kk) a[kk] = *(const f16x8*)(ab + kk * 512);

    float nL[4], nS[4];
    #pragma unroll
    for (int r = 0; r < 4; ++r) { nL[r] = 0.f; nS[r] = 0.f; }

    const _Float16* bb = xf + (size_t)ct0 * 2048 + lane * 8;

    auto loadB = [&](f16x8 (&b)[4], int g) {
        const _Float16* bp = bb + (size_t)g * 2048;
        #pragma unroll
        for (int kk = 0; kk < 4; ++kk) b[kk] = *(const f16x8*)(bp + kk * 512);
    };
    auto compute = [&](f16x8 (&b)[4]) {
        f32x4 acc = {0.f, 0.f, 0.f, 0.f};
        #pragma unroll
        for (int kk = 0; kk < 4; ++kk)
            acc = __builtin_amdgcn_mfma_f32_16x16x32_f16(a[kk], b[kk], acc, 0, 0, 0);
        #pragma unroll
        for (int r = 0; r < 4; ++r) {
            float d2s = fmaf(-2.0f * K2, acc[r], 2.0f * K2);   // (20*log2e)^2 * d^2
            float ds  = __builtin_amdgcn_sqrtf(d2s);           // NaN on self, masked below
            float tt  = __builtin_amdgcn_exp2f(-ds);           // exp(-20 d)
            tt = (d2s < DTHR) ? 0.0f : tt;                     // exact self-pair exclusion
            nS[r] += tt;
            nL[r] = fmaf(tt, tt, nL[r]);                       // exp(-40 d)
        }
    };

    // 16 col-tiles, 1-ahead register double buffer (wrap reload on last: harmless)
    f16x8 b0[4], b1[4];
    loadB(b0, 0);
    for (int g = 0; g < 16; g += 2) {
        loadB(b1, g + 1);
        compute(b0);
        loadB(b0, (g + 2) & 15);
        compute(b1);
    }

    // reduce across the 16 column-lanes; C/D map: col=lane&15, row=(lane>>4)*4+r
    #pragma unroll
    for (int r = 0; r < 4; ++r) {
        float aa = nL[r], ss = nS[r];
        #pragma unroll
        for (int m = 1; m < 16; m <<= 1) {
            aa += __shfl_xor(aa, m, 64);
            ss += __shfl_xor(ss, m, 64);
        }
        if ((lane & 15) == 0) {
            const int row = i0 + (lane >> 4) * 4 + r;
            atomicAdd(&sums[row], aa);
            atomicAdd(&sums[NROWS + row], ss);
        }
    }
}

// ---- finalize + positive-pair correction, 8 threads per row (1024 waves).
//      (byte-identical to the round-7/8 verified kernel) ----
__global__ void finalize_kernel(const _Float16* __restrict__ xf,
                                const float* __restrict__ sums,
                                float* __restrict__ out) {
    const int tid = threadIdx.x;
    const int i = blockIdx.x * 32 + (tid >> 3);   // row
    const int j = tid & 7;                        // partner slot
    const int g = i >> 4, ri = i & 15, ii = i & 7;
    const _Float16* base = xf + (size_t)g * 2048;

    float pL = 0.f, pS = 0.f, subL = 0.f, subS = 0.f;
    if (j != ii) {
        const int rj = ri - ii + j;               // same 16-row group (classes 8-aligned)
        float dot = 0.f;
        #pragma unroll
        for (int kk = 0; kk < 4; ++kk) {
            #pragma unroll
            for (int h = 0; h < 4; ++h) {
                f16x8 av = *(const f16x8*)(base + kk * 512 + ((h << 4) | ri) * 8);
                f16x8 bv = *(const f16x8*)(base + kk * 512 + ((h << 4) | rj) * 8);
#if HAVE_FDOT2
                #pragma unroll
                for (int u = 0; u < 4; ++u) {
                    f16x2 pa = { av[2 * u], av[2 * u + 1] };
                    f16x2 pb = { bv[2 * u], bv[2 * u + 1] };
                    dot = __builtin_amdgcn_fdot2(pa, pb, dot, false);
                }
#else
                #pragma unroll
                for (int u = 0; u < 8; ++u)
                    dot = fmaf((float)av[u], (float)bv[u], dot);
#endif
            }
        }
        float d2 = fmaf(-2.f, dot, 2.f);
        float d  = sqrtf(fmaxf(d2, 1e-12f));           // reference clamp
        float tt = __builtin_amdgcn_exp2f(-d * K20);   // exp(-20 d)
        pS = __builtin_amdgcn_exp2f(d * K20);          // exp(+20 d)
        pL = tt * tt;
        float tp = (d2 * K2 < DTHR) ? 0.f : tt;        // what pair_kernel added
        subS = tp;
        subL = tp * tp;
    }

    // combine the 8 partner slots of this row
    #pragma unroll
    for (int m = 1; m < 8; m <<= 1) {
        pL   += __shfl_xor(pL, m, 64);
        pS   += __shfl_xor(pS, m, 64);
        subL += __shfl_xor(subL, m, 64);
        subS += __shfl_xor(subS, m, 64);
    }

    float v = 0.f;
    if (j == 0) {
        float nLv = sums[i] - subL;
        float nSv = sums[NROWS + i] - subS;
        float aLr  = 1.0f - pL / (pL + nLv);
        float posL = logf(pS) - 16.0f;    // log(sum exp(20(d-0.8)))
        float negL = logf(nSv) + 22.0f;   // log(sum exp(20(1.1-d)))
        v = aLr * (posL + negL);
    }
    #pragma unroll
    for (int m = 8; m < 64; m <<= 1) v += __shfl_xor(v, m, 64);

    __shared__ float partial[4];
    int wv = tid >> 6, lane = tid & 63;
    if (lane == 0) partial[wv] = v;
    __syncthreads();
    if (tid == 0) {
        float s = partial[0] + partial[1] + partial[2] + partial[3];
        atomicAdd(out, s * (1.0f / NROWS));
    }
}

extern "C" void kernel_launch(void* const* d_in, const int* in_sizes, int n_in,
                              void* d_out, int out_size, void* d_ws, size_t ws_size,
                              hipStream_t stream) {
    const float* x = (const float*)d_in[0];
    float* out = (float*)d_out;

    _Float16* xf = (_Float16*)d_ws;              // 2 MB, fragment-major
    float* sums  = (float*)(xf + NROWS * DDIM);  // 2*NROWS floats

    convert_kernel<<<NROWS * DDIM / (256 * 4), 256, 0, stream>>>(x, xf, sums, out);
    dim3 grid(NROWS / 64, NROWS / 256);          // 128 x 32 = 4096 uniform blocks
    pair_kernel<<<grid, 256, 0, stream>>>(xf, sums);
    finalize_kernel<<<NROWS / 32, 256, 0, stream>>>(xf, sums, out);
}

// Round 10
// 89.163 us; speedup vs baseline: 1.1824x; 1.1824x over previous
//
#include <hip/hip_runtime.h>
#include <math.h>

#define NROWS 8192
#define DDIM  128
#define K20   28.853900817779268f        // 20 * log2(e)
#define K2    (K20 * K20)                // 832.5476
#define DTHR  8.3255f                    // 0.01 * K2 (finalize subtraction mimic only)

typedef _Float16 f16x8 __attribute__((ext_vector_type(8)));
typedef _Float16 f16x4 __attribute__((ext_vector_type(4)));
typedef _Float16 f16x2 __attribute__((ext_vector_type(2)));
typedef float    f32x4 __attribute__((ext_vector_type(4)));

#ifndef __has_builtin
#define __has_builtin(x) 0
#endif
#if __has_builtin(__builtin_amdgcn_fdot2)
#define HAVE_FDOT2 1
#else
#define HAVE_FDOT2 0
#endif

// Fragment-major layout for mfma_f32_16x16x32_f16 (16-row groups):
//   xf[g*2048 + kk*512 + l*8 + j] = x[i = g*16 + (l&15)][k = kk*32 + (l>>4)*8 + j]
//
// ZERO-GLOBAL-ATOMIC accumulation (the R9 diagnosis: device-scope atomicAdd
// serialization ~200cy/RMW x ~500/line was the occupancy-invariant ~40us wall):
//   rowPart[32][8192] (float2 L,S): slot by  -> direct (j>i) row sums of block (bx,by)
//   colPart[64][8192] (float2 L,S): slot bx  -> mirrored col sums of block (bx,by)
// Single writer per slot element. Kept blocks: 2*by+2 > bx. Read sets match
// written sets exactly (no zeroing):
//   row i (bx=i>>7, by_i=i>>8):
//     n = sum_{by >= bx>>1} rowPart[by][i] + sum_{bx2 < 2*by_i+2} colPart[bx2][i]

// ---- fp32 -> f16 frag-major transform + zero out ----
__global__ void convert_kernel(const float* __restrict__ x,
                               _Float16* __restrict__ xf,
                               float* __restrict__ out) {
    int idx = (blockIdx.x * 256 + threadIdx.x) * 4;    // flat (i,k) element index
    float4 v = *(const float4*)(x + idx);
    f16x4 h = { (_Float16)v.x, (_Float16)v.y, (_Float16)v.z, (_Float16)v.w };
    const int i = idx >> 7, k = idx & 127;             // k multiple of 4
    const int lane = (((k >> 3) & 3) << 4) | (i & 15);
    const int dst = (i >> 4) * 2048 + (k >> 5) * 512 + lane * 8 + (k & 7);
    *(f16x4*)(xf + dst) = h;
    if (blockIdx.x == 0 && threadIdx.x == 0) out[0] = 0.0f;
}

// ---- symmetric pair kernel (round-7 verified inner loop, atomic-free I/O).
//      Only strictly-upper elements (j > i) accumulate: direct into row i
//      (row-sum reduce -> rowPart slot) and mirrored into row j (col sums via
//      LDS -> colPart slot). Lower-triangle blocks exit immediately. ----
__global__ __launch_bounds__(256, 4) void pair_kernel(
        const _Float16* __restrict__ xf,
        float2* __restrict__ rowPart,
        float2* __restrict__ colPart) {
    // keep block iff its 256-col segment reaches above the diagonal
    if (2 * blockIdx.y + 2 <= blockIdx.x) return;

    __shared__ float shcL[4][256], shcS[4][256];

    const int w = threadIdx.x >> 6;
    const int lane = threadIdx.x & 63;
    const int ig = blockIdx.x * 4 + w;            // 32-row strip, 0..255
    const int i0 = ig * 32;
    const int ct0 = blockIdx.y * 16;              // first 16-col tile of segment

    // A fragments resident: 2 strips x 4 k-chunks, one 1 KB coalesced load each
    const _Float16* ab = xf + (size_t)(ig * 2) * 2048 + lane * 8;
    f16x8 a0[4], a1[4];
    #pragma unroll
    for (int kk = 0; kk < 4; ++kk) {
        a0[kk] = *(const f16x8*)(ab + kk * 512);
        a1[kk] = *(const f16x8*)(ab + 2048 + kk * 512);
    }

    float nL[8], nS[8];
    #pragma unroll
    for (int r = 0; r < 8; ++r) { nL[r] = 0.f; nS[r] = 0.f; }

    const _Float16* bb = xf + (size_t)ct0 * 2048 + lane * 8;

    f16x8 b0[4], b1[4];
    #pragma unroll
    for (int kk = 0; kk < 4; ++kk) b0[kk] = *(const f16x8*)(bb + kk * 512);

    auto compute = [&](f16x8 (&b)[4], int g) {
        f32x4 acc0 = {0.f,0.f,0.f,0.f}, acc1 = {0.f,0.f,0.f,0.f};
        #pragma unroll
        for (int kk = 0; kk < 4; ++kk) {
            acc0 = __builtin_amdgcn_mfma_f32_16x16x32_f16(a0[kk], b[kk], acc0, 0, 0, 0);
            acc1 = __builtin_amdgcn_mfma_f32_16x16x32_f16(a1[kk], b[kk], acc1, 0, 0, 0);
        }
        const int jcol = (ct0 + g) * 16 + (lane & 15);   // this lane's column
        float cs = 0.f, cl = 0.f;
        #pragma unroll
        for (int s = 0; s < 2; ++s) {
            const int ib = i0 + s * 16 + ((lane >> 4) << 2);  // C/D row base (m89/m91)
            #pragma unroll
            for (int r = 0; r < 4; ++r) {
                float acc = s ? acc1[r] : acc0[r];            // static indices
                float d2s = fmaf(-2.0f * K2, acc, 2.0f * K2); // (20*log2e)^2 * d^2
                float ds  = __builtin_amdgcn_sqrtf(d2s);      // NaN on self, masked below
                float tt  = __builtin_amdgcn_exp2f(-ds);      // exp(-20 d)
                tt = (jcol > ib + r) ? tt : 0.0f;             // strictly-upper only
                nS[s * 4 + r] += tt;
                nL[s * 4 + r] = fmaf(tt, tt, nL[s * 4 + r]);  // exp(-40 d)
                cs += tt;
                cl = fmaf(tt, tt, cl);
            }
        }
        // mirror: reduce over the wave's 32 rows (row groups at lane bits 4,5)
        cs += __shfl_xor(cs, 16, 64);  cl += __shfl_xor(cl, 16, 64);
        cs += __shfl_xor(cs, 32, 64);  cl += __shfl_xor(cl, 32, 64);
        if (lane < 16) { shcS[w][g * 16 + lane] = cs; shcL[w][g * 16 + lane] = cl; }
    };

    // 16 col-tiles, 1-ahead register double buffer (wrap reload on last: harmless)
    for (int g = 0; g < 16; g += 2) {
        const _Float16* p1 = bb + (size_t)(g + 1) * 2048;
        #pragma unroll
        for (int kk = 0; kk < 4; ++kk) b1[kk] = *(const f16x8*)(p1 + kk * 512);
        compute(b0, g);
        const _Float16* p2 = bb + (size_t)((g + 2) & 15) * 2048;
        #pragma unroll
        for (int kk = 0; kk < 4; ++kk) b0[kk] = *(const f16x8*)(p2 + kk * 512);
        compute(b1, g + 1);
    }

    // direct row sums -> unique slot rowPart[by][row] (plain store, no atomic)
    const size_t rslot = (size_t)blockIdx.y * NROWS;
    #pragma unroll
    for (int s = 0; s < 2; ++s) {
        #pragma unroll
        for (int r = 0; r < 4; ++r) {
            float aa = nL[s * 4 + r], ss = nS[s * 4 + r];
            #pragma unroll
            for (int m = 1; m < 16; m <<= 1) {
                aa += __shfl_xor(aa, m, 64);
                ss += __shfl_xor(ss, m, 64);
            }
            if ((lane & 15) == 0) {
                const int row = i0 + s * 16 + (lane >> 4) * 4 + r;
                rowPart[rslot + row] = make_float2(aa, ss);
            }
        }
    }

    // mirrored col sums -> unique slot colPart[bx][col] (plain store)
    __syncthreads();
    {
        const int c = threadIdx.x;                 // 256 threads = 256 segment cols
        const int col = ct0 * 16 + c;
        float mL = shcL[0][c] + shcL[1][c] + shcL[2][c] + shcL[3][c];
        float mS = shcS[0][c] + shcS[1][c] + shcS[2][c] + shcS[3][c];
        colPart[(size_t)blockIdx.x * NROWS + col] = make_float2(mL, mS);
    }
}

// ---- finalize: gather partials (coalesced, 8 threads/row) + positive-pair
//      correction (round-7 verified dot path) + loss ----
__global__ void finalize_kernel(const _Float16* __restrict__ xf,
                                const float2* __restrict__ rowPart,
                                const float2* __restrict__ colPart,
                                float* __restrict__ out) {
    const int tid = threadIdx.x;
    const int i = blockIdx.x * 32 + (tid >> 3);   // row
    const int j = tid & 7;                        // partner / gather slot
    const int g = i >> 4, ri = i & 15, ii = i & 7;
    const _Float16* base = xf + (size_t)g * 2048;

    // ---- gather negative-pair partials (only written slots are read) ----
    const int bx = i >> 7, byi = i >> 8;
    float nl = 0.f, ns = 0.f;
    for (int by = (bx >> 1) + j; by < 32; by += 8) {
        float2 v = rowPart[(size_t)by * NROWS + i];
        nl += v.x; ns += v.y;
    }
    const int bxe = 2 * byi + 2;                  // exclusive bound, <= 64
    for (int b2 = j; b2 < bxe; b2 += 8) {
        float2 v = colPart[(size_t)b2 * NROWS + i];
        nl += v.x; ns += v.y;
    }

    // ---- positive-pair terms: this thread's single partner jj = j ----
    float pL = 0.f, pS = 0.f, subL = 0.f, subS = 0.f;
    if (j != ii) {
        const int rj = ri - ii + j;               // same 16-row group (classes 8-aligned)
        float dot = 0.f;
        #pragma unroll
        for (int kk = 0; kk < 4; ++kk) {
            #pragma unroll
            for (int h = 0; h < 4; ++h) {
                f16x8 av = *(const f16x8*)(base + kk * 512 + ((h << 4) | ri) * 8);
                f16x8 bv = *(const f16x8*)(base + kk * 512 + ((h << 4) | rj) * 8);
#if HAVE_FDOT2
                #pragma unroll
                for (int u = 0; u < 4; ++u) {
                    f16x2 pa = { av[2 * u], av[2 * u + 1] };
                    f16x2 pb = { bv[2 * u], bv[2 * u + 1] };
                    dot = __builtin_amdgcn_fdot2(pa, pb, dot, false);
                }
#else
                #pragma unroll
                for (int u = 0; u < 8; ++u)
                    dot = fmaf((float)av[u], (float)bv[u], dot);
#endif
            }
        }
        float d2 = fmaf(-2.f, dot, 2.f);
        float d  = sqrtf(fmaxf(d2, 1e-12f));           // reference clamp
        float tt = __builtin_amdgcn_exp2f(-d * K20);   // exp(-20 d)
        pS = __builtin_amdgcn_exp2f(d * K20);          // exp(+20 d)
        pL = tt * tt;
        float tp = (d2 * K2 < DTHR) ? 0.f : tt;        // what pair_kernel added
        subS = tp;
        subL = tp * tp;
    }

    // combine the 8 slots of this row (gather partials + positive terms)
    #pragma unroll
    for (int m = 1; m < 8; m <<= 1) {
        nl   += __shfl_xor(nl, m, 64);
        ns   += __shfl_xor(ns, m, 64);
        pL   += __shfl_xor(pL, m, 64);
        pS   += __shfl_xor(pS, m, 64);
        subL += __shfl_xor(subL, m, 64);
        subS += __shfl_xor(subS, m, 64);
    }

    float v = 0.f;
    if (j == 0) {
        float nLv = nl - subL;
        float nSv = ns - subS;
        float aLr  = 1.0f - pL / (pL + nLv);
        float posL = logf(pS) - 16.0f;    // log(sum exp(20(d-0.8)))
        float negL = logf(nSv) + 22.0f;   // log(sum exp(20(1.1-d)))
        v = aLr * (posL + negL);
    }
    #pragma unroll
    for (int m = 8; m < 64; m <<= 1) v += __shfl_xor(v, m, 64);

    __shared__ float partial[4];
    int wv = tid >> 6, lane = tid & 63;
    if (lane == 0) partial[wv] = v;
    __syncthreads();
    if (tid == 0) {
        float s = partial[0] + partial[1] + partial[2] + partial[3];
        atomicAdd(out, s * (1.0f / NROWS));
    }
}

extern "C" void kernel_launch(void* const* d_in, const int* in_sizes, int n_in,
                              void* d_out, int out_size, void* d_ws, size_t ws_size,
                              hipStream_t stream) {
    const float* x = (const float*)d_in[0];
    float* out = (float*)d_out;

    _Float16* xf = (_Float16*)d_ws;                  // 2 MB, fragment-major
    float2* rowPart = (float2*)(xf + NROWS * DDIM);  // [32][8192] 2 MB
    float2* colPart = rowPart + 32 * NROWS;          // [64][8192] 4 MB  (8 MB total)

    convert_kernel<<<NROWS * DDIM / (256 * 4), 256, 0, stream>>>(x, xf, out);
    dim3 grid(NROWS / 128, NROWS / 256);             // 64 x 32; lower blocks exit
    pair_kernel<<<grid, 256, 0, stream>>>(xf, rowPart, colPart);
    finalize_kernel<<<NROWS / 32, 256, 0, stream>>>(xf, rowPart, colPart, out);
}